// Round 1
// baseline (891.998 us; speedup 1.0000x reference)
//
#include <hip/hip_runtime.h>

// NCC loss: 9^3 box sums of {I, J, I*I, J*J, I*J}, per-voxel cc, -mean(cc).
// Dims: C=2, D=192, H=224, W=192, fp32. Separable box filter:
//   K1: H-direction running sum of the 5 product fields (register ring).
//   K2: W-sum (LDS 9-tap) + D-sum (register ring) + cc + reduction.

#define C2   2
#define DDIM 192
#define HDIM 224
#define WDIM 192
#define HWN  (HDIM*WDIM)              // 43008
#define VOL  ((size_t)DDIM*HWN)       // 8257536
#define RAD  4
#define WINV (1.0f/729.0f)

#define HT1  32   // K1 h-chunk
#define WT   64   // K2 w-tile
#define HT   4    // K2 h-tile

// ---------------- K1: H-direction box sum of 5 product fields ----------------
// grid: (d rows in [dbeg,dend), H/HT1, C2); block: 192 threads (w)
// buf layout: [f][c][bd][h][w], bd = d - d0 + 4, fstride = 2*bufD*HWN
__global__ __launch_bounds__(192)
void k_hsum(const float* __restrict__ I, const float* __restrict__ J,
            float* __restrict__ buf, int d0, int dbeg, int bufD)
{
    const int w  = threadIdx.x;
    const int d  = dbeg + blockIdx.x;
    const int h0 = blockIdx.y * HT1;
    const int c  = blockIdx.z;

    const float* Ib = I + (size_t)c*VOL + (size_t)d*HWN + w;
    const float* Jb = J + (size_t)c*VOL + (size_t)d*HWN + w;

    float ring[5][9];
    float rs[5] = {0.f,0.f,0.f,0.f,0.f};

    // warm-up: ring slots 0..7 = products at rows h0-4 .. h0+3 (zero padded)
    #pragma unroll
    for (int k = 0; k < 8; ++k) {
        const int h = h0 - RAD + k;
        float iv = 0.f, jv = 0.f;
        if (h >= 0 && h < HDIM) { iv = Ib[(size_t)h*WDIM]; jv = Jb[(size_t)h*WDIM]; }
        const float pr[5] = {iv, jv, iv*iv, jv*jv, iv*jv};
        #pragma unroll
        for (int f = 0; f < 5; ++f) { ring[f][k] = pr[f]; rs[f] += pr[f]; }
    }

    const size_t fstride = (size_t)C2*bufD*HWN;
    float* ob = buf + ((size_t)c*bufD + (size_t)(d - d0 + RAD))*HWN + w;

    int i = 0;
    while (i < HT1) {
        #pragma unroll
        for (int p = 0; p < 9; ++p) {   // i == p (mod 9) whenever body runs
            if (i < HT1) {
                const int h  = h0 + i;
                const int hf = h + RAD;
                float iv = 0.f, jv = 0.f;
                if (hf < HDIM) { iv = Ib[(size_t)hf*WDIM]; jv = Jb[(size_t)hf*WDIM]; }
                const float pr[5] = {iv, jv, iv*iv, jv*jv, iv*jv};
                #pragma unroll
                for (int f = 0; f < 5; ++f) {
                    rs[f] += pr[f];                       // window sum at h
                    ob[(size_t)f*fstride + (size_t)h*WDIM] = rs[f];
                    rs[f] -= ring[f][p];                  // drop row h-4
                    ring[f][(p+8)%9] = pr[f];             // keep row h+4
                }
                ++i;
            }
        }
    }
}

// ------- K2: W-sum (LDS) + D-sum (register ring) + cc + block reduce -------
// grid: (W/WT, H/HT, nsub*C2); block: (WT, HT)
__global__ __launch_bounds__(256)
void k_wdsum(const float* __restrict__ buf, double* __restrict__ gacc,
             int d0, int bufD, int nsub, int DS)
{
    const int tx  = threadIdx.x;            // w within tile
    const int ty  = threadIdx.y;            // h within tile
    const int tid = ty*WT + tx;
    const int w0  = blockIdx.x*WT;
    const int h0  = blockIdx.y*HT;
    const int cq  = blockIdx.z / nsub;
    const int ds0 = d0 + (blockIdx.z % nsub)*DS;

    const size_t fstride = (size_t)C2*bufD*HWN;
    const float* cb = buf + (size_t)cq*bufD*HWN;

    __shared__ float tile[5][HT][WT+8];     // 5.76 KB
    __shared__ float wred[4];

    float ring[5][9];
    float rs[5] = {0.f,0.f,0.f,0.f,0.f};
    float acc = 0.f;

    // ---- warm-up: W-sums for slices ds0-4 .. ds0+3 ----
    #pragma unroll
    for (int k = 0; k < 8; ++k) {
        const int dd = ds0 - RAD + k;
        {
            const bool dok = (dd >= 0) & (dd < DDIM);
            const float* pp = cb + (size_t)(dd - d0 + RAD)*HWN;
            for (int t = tid; t < 5*HT*(WT+8); t += WT*HT) {
                const int f = t / (HT*(WT+8));
                const int r = (t / (WT+8)) % HT;
                const int j = t % (WT+8);
                const int w = w0 + j - RAD;
                float v = 0.f;
                if (dok && (unsigned)w < (unsigned)WDIM)
                    v = pp[(size_t)f*fstride + (size_t)(h0+r)*WDIM + w];
                tile[f][r][j] = v;
            }
        }
        __syncthreads();
        #pragma unroll
        for (int f = 0; f < 5; ++f) {
            float s = 0.f;
            #pragma unroll
            for (int q = 0; q < 9; ++q) s += tile[f][ty][tx+q];
            ring[f][k] = s; rs[f] += s;
        }
        __syncthreads();
    }

    // ---- main march along D ----
    int i = 0;
    while (i < DS) {
        #pragma unroll
        for (int p = 0; p < 9; ++p) {   // i == p (mod 9) whenever body runs
            if (i < DS) {
                const int dd = ds0 + i + RAD;
                {
                    const bool dok = (dd < DDIM);
                    const float* pp = cb + (size_t)(dd - d0 + RAD)*HWN;
                    for (int t = tid; t < 5*HT*(WT+8); t += WT*HT) {
                        const int f = t / (HT*(WT+8));
                        const int r = (t / (WT+8)) % HT;
                        const int j = t % (WT+8);
                        const int w = w0 + j - RAD;
                        float v = 0.f;
                        if (dok && (unsigned)w < (unsigned)WDIM)
                            v = pp[(size_t)f*fstride + (size_t)(h0+r)*WDIM + w];
                        tile[f][r][j] = v;
                    }
                }
                __syncthreads();
                float S[5];
                #pragma unroll
                for (int f = 0; f < 5; ++f) {
                    float s = 0.f;
                    #pragma unroll
                    for (int q = 0; q < 9; ++q) s += tile[f][ty][tx+q];
                    rs[f] += s;               // full 9x9x9 sum at (dd-4)
                    S[f] = rs[f];
                    rs[f] -= ring[f][p];      // drop slice dd-8
                    ring[f][(p+8)%9] = s;     // keep slice dd
                }
                const float uI    = S[0]*WINV;
                const float uJ    = S[1]*WINV;
                const float cross = S[4] - uJ*S[0];   // == IJ - I*J/729 (exact algebra)
                const float Iv    = S[2] - uI*S[0];
                const float Jv    = S[3] - uJ*S[1];
                const float cc    = cross*cross / (Iv*Jv + 1e-5f);
                acc += cc;
                __syncthreads();
                ++i;
            }
        }
    }

    // ---- block reduction -> one double atomic per block ----
    #pragma unroll
    for (int off = 32; off > 0; off >>= 1) acc += __shfl_down(acc, off);
    if ((tid & 63) == 0) wred[tid >> 6] = acc;
    __syncthreads();
    if (tid == 0) {
        const float s = wred[0] + wred[1] + wred[2] + wred[3];
        atomicAdd(gacc, (double)s);
    }
}

__global__ void k_fin(const double* __restrict__ gacc, float* __restrict__ out)
{
    out[0] = (float)(-gacc[0] / (double)((size_t)C2*DDIM*HDIM*WDIM));
}

extern "C" void kernel_launch(void* const* d_in, const int* in_sizes, int n_in,
                              void* d_out, int out_size, void* d_ws, size_t ws_size,
                              hipStream_t stream)
{
    if (n_in < 2) return;
    const float* I = (const float*)d_in[0];
    const float* J = (const float*)d_in[1];
    float* out = (float*)d_out;
    double* gacc = (double*)d_ws;
    float* buf = (float*)((char*)d_ws + 256);

    // choose D-chunk so the 5-field H-summed buffer fits ws
    static const int cands[] = {192, 96, 48, 24, 12, 6, 4, 2, 1};
    int Dc = 0;
    for (int c : cands) {
        const size_t need = 256 + (size_t)5*C2*(c+8)*HWN*sizeof(float);
        if (need <= ws_size) { Dc = c; break; }
    }
    if (Dc == 0) return;  // ws too small (<16 MB) — cannot run

    hipMemsetAsync(d_ws, 0, 256, stream);   // zero the double accumulator

    const int DS   = (Dc < 48) ? Dc : 48;   // per-block D march length in K2
    const int nsub = Dc / DS;
    const int bufD = Dc + 8;

    for (int d0 = 0; d0 < DDIM; d0 += Dc) {
        const int dbeg = (d0 - RAD < 0) ? 0 : d0 - RAD;
        const int dend = (d0 + Dc + RAD > DDIM) ? DDIM : d0 + Dc + RAD;
        dim3 g1(dend - dbeg, HDIM/HT1, C2);
        k_hsum<<<g1, dim3(192,1,1), 0, stream>>>(I, J, buf, d0, dbeg, bufD);
        dim3 g2(WDIM/WT, HDIM/HT, nsub*C2);
        k_wdsum<<<g2, dim3(WT,HT,1), 0, stream>>>(buf, gacc, d0, bufD, nsub, DS);
    }
    k_fin<<<1,1,0,stream>>>(gacc, out);
}

// Round 2
// 226.753 us; speedup vs baseline: 3.9338x; 3.9338x over previous
//
#include <hip/hip_runtime.h>

// NCC loss: 9^3 box sums of {I, J, I*I, J*J, I*J}, per-voxel cc, -mean(cc).
// Dims: C=2, D=192, H=224, W=192, fp32. Separable box filter:
//   K1 (k_hwsum): H-sum (register ring) + W-sum (LDS 9-tap, double-buffered,
//                 one barrier per h-step) -> writes 2D-summed fields.
//   K2 (k_dsum):  D-sum only — barrier-free streaming register ring + cc + reduce.

#define C2   2
#define DDIM 192
#define HDIM 224
#define WDIM 192
#define HWN  (HDIM*WDIM)              // 43008
#define VOL  ((size_t)DDIM*HWN)       // 8257536
#define RAD  4
#define WINV (1.0f/729.0f)

#define HT1  32   // K1 h-chunk per block

// ---------------- K1: H-sum + W-sum of 5 product fields ----------------
// grid: (d rows in [dbeg,dend), HDIM/HT1, C2); block: 192 threads (w)
// buf layout: [f][c][bd][h][w], bd = d - d0 + 4, fstride = C2*bufD*HWN
__global__ __launch_bounds__(192)
void k_hwsum(const float* __restrict__ I, const float* __restrict__ J,
             float* __restrict__ buf, int d0, int dbeg, int bufD)
{
    const int w  = threadIdx.x;
    const int d  = dbeg + blockIdx.x;
    const int h0 = blockIdx.y * HT1;
    const int c  = blockIdx.z;

    __shared__ float row[2][5][WDIM + 8];   // double-buffered H-sum row, 8 KB
    if (w < 8) {                            // zero the W-halo pads once
        const int pos = (w < 4) ? w : (WDIM + w);
        #pragma unroll
        for (int b = 0; b < 2; ++b)
            #pragma unroll
            for (int f = 0; f < 5; ++f) row[b][f][pos] = 0.f;
    }
    __syncthreads();

    const float* Ib = I + (size_t)c*VOL + (size_t)d*HWN + w;
    const float* Jb = J + (size_t)c*VOL + (size_t)d*HWN + w;

    float ring[5][9];
    float rs[5] = {0.f,0.f,0.f,0.f,0.f};

    // warm-up: ring slots 0..7 = products at rows h0-4 .. h0+3 (zero padded)
    #pragma unroll
    for (int k = 0; k < 8; ++k) {
        const int h = h0 - RAD + k;
        float iv = 0.f, jv = 0.f;
        if (h >= 0 && h < HDIM) { iv = Ib[(size_t)h*WDIM]; jv = Jb[(size_t)h*WDIM]; }
        const float pr[5] = {iv, jv, iv*iv, jv*jv, iv*jv};
        #pragma unroll
        for (int f = 0; f < 5; ++f) { ring[f][k] = pr[f]; rs[f] += pr[f]; }
    }

    const size_t fstride = (size_t)C2*bufD*HWN;
    float* ob = buf + ((size_t)c*bufD + (size_t)(d - d0 + RAD))*HWN + w;

    int i = 0;
    while (i < HT1) {
        #pragma unroll
        for (int p = 0; p < 9; ++p) {   // i == p (mod 9) whenever body runs
            if (i < HT1) {
                const int h  = h0 + i;
                const int hf = h + RAD;
                float iv = 0.f, jv = 0.f;
                if (hf < HDIM) { iv = Ib[(size_t)hf*WDIM]; jv = Jb[(size_t)hf*WDIM]; }
                const float pr[5] = {iv, jv, iv*iv, jv*jv, iv*jv};
                float (* __restrict__ rb)[WDIM+8] = row[h & 1];
                #pragma unroll
                for (int f = 0; f < 5; ++f) {
                    rs[f] += pr[f];                 // H window sum at h
                    rb[f][RAD + w] = rs[f];
                    rs[f] -= ring[f][p];            // drop row h-4
                    ring[f][(p+8)%9] = pr[f];       // keep row h+4
                }
                __syncthreads();                    // single barrier: dbuf-safe
                #pragma unroll
                for (int f = 0; f < 5; ++f) {
                    float s = 0.f;
                    #pragma unroll
                    for (int q = 0; q < 9; ++q) s += rb[f][w + q];
                    ob[(size_t)f*fstride + (size_t)h*WDIM] = s;
                }
                ++i;
            }
        }
    }
}

// -------- K2: D-sum (register ring) + cc + block reduce — no LDS, no syncs --------
// grid: (HWN/256, nsub, C2); block: 256 threads
__global__ __launch_bounds__(256)
void k_dsum(const float* __restrict__ buf, double* __restrict__ gacc,
            int d0, int bufD, int DS)
{
    const int tid = threadIdx.x;
    const int pix = blockIdx.x*256 + tid;     // (h,w) flat, HWN = 168*256 exact
    const int c   = blockIdx.z;
    const int ds0 = d0 + blockIdx.y*DS;

    const size_t fstride = (size_t)C2*bufD*HWN;
    const float* base = buf + (size_t)c*bufD*HWN + pix;

    float ring[5][9];
    float rs[5] = {0.f,0.f,0.f,0.f,0.f};
    float acc = 0.f;

    // warm-up: slices ds0-4 .. ds0+3
    #pragma unroll
    for (int k = 0; k < 8; ++k) {
        const int dd = ds0 - RAD + k;
        float v[5] = {0.f,0.f,0.f,0.f,0.f};
        if ((unsigned)dd < (unsigned)DDIM) {
            const float* pp = base + (size_t)(dd - d0 + RAD)*HWN;
            #pragma unroll
            for (int f = 0; f < 5; ++f) v[f] = pp[(size_t)f*fstride];
        }
        #pragma unroll
        for (int f = 0; f < 5; ++f) { ring[f][k] = v[f]; rs[f] += v[f]; }
    }

    int i = 0;
    while (i < DS) {
        #pragma unroll
        for (int p = 0; p < 9; ++p) {   // i == p (mod 9) whenever body runs
            if (i < DS) {
                const int dd = ds0 + i + RAD;
                float v[5] = {0.f,0.f,0.f,0.f,0.f};
                if (dd < DDIM) {
                    const float* pp = base + (size_t)(dd - d0 + RAD)*HWN;
                    #pragma unroll
                    for (int f = 0; f < 5; ++f) v[f] = pp[(size_t)f*fstride];
                }
                float S[5];
                #pragma unroll
                for (int f = 0; f < 5; ++f) {
                    rs[f] += v[f];              // full 9x9x9 sum at dd-4
                    S[f] = rs[f];
                    rs[f] -= ring[f][p];        // drop slice dd-8
                    ring[f][(p+8)%9] = v[f];    // keep slice dd
                }
                const float uI    = S[0]*WINV;
                const float uJ    = S[1]*WINV;
                const float cross = S[4] - uJ*S[0];
                const float Iv    = S[2] - uI*S[0];
                const float Jv    = S[3] - uJ*S[1];
                acc += cross*cross / (Iv*Jv + 1e-5f);
                ++i;
            }
        }
    }

    // block reduction -> one double atomic per block
    __shared__ float wred[4];
    #pragma unroll
    for (int off = 32; off > 0; off >>= 1) acc += __shfl_down(acc, off);
    if ((tid & 63) == 0) wred[tid >> 6] = acc;
    __syncthreads();
    if (tid == 0) {
        const float s = wred[0] + wred[1] + wred[2] + wred[3];
        atomicAdd(gacc, (double)s);
    }
}

__global__ void k_fin(const double* __restrict__ gacc, float* __restrict__ out)
{
    out[0] = (float)(-gacc[0] / (double)((size_t)C2*DDIM*HDIM*WDIM));
}

extern "C" void kernel_launch(void* const* d_in, const int* in_sizes, int n_in,
                              void* d_out, int out_size, void* d_ws, size_t ws_size,
                              hipStream_t stream)
{
    if (n_in < 2) return;
    const float* I = (const float*)d_in[0];
    const float* J = (const float*)d_in[1];
    float* out = (float*)d_out;
    double* gacc = (double*)d_ws;
    float* buf = (float*)((char*)d_ws + 256);

    // choose D-chunk so the 5-field 2D-summed buffer fits ws
    static const int cands[] = {192, 96, 48, 24, 12, 6, 4, 2, 1};
    int Dc = 0;
    for (int c : cands) {
        const size_t need = 256 + (size_t)5*C2*(c+8)*HWN*sizeof(float);
        if (need <= ws_size) { Dc = c; break; }
    }
    if (Dc == 0) return;  // ws too small (<16 MB) — cannot run

    hipMemsetAsync(d_ws, 0, 256, stream);   // zero the double accumulator

    const int DS   = (Dc >= 24 && (Dc % 24) == 0) ? 24 : Dc;  // K2 sub-chunk
    const int nsub = Dc / DS;
    const int bufD = Dc + 8;

    for (int d0 = 0; d0 < DDIM; d0 += Dc) {
        const int dbeg = (d0 - RAD < 0) ? 0 : d0 - RAD;
        const int dend = (d0 + Dc + RAD > DDIM) ? DDIM : d0 + Dc + RAD;
        dim3 g1(dend - dbeg, HDIM/HT1, C2);
        k_hwsum<<<g1, dim3(192,1,1), 0, stream>>>(I, J, buf, d0, dbeg, bufD);
        dim3 g2(HWN/256, nsub, C2);
        k_dsum<<<g2, dim3(256,1,1), 0, stream>>>(buf, gacc, d0, bufD, DS);
    }
    k_fin<<<1,1,0,stream>>>(gacc, out);
}

// Round 3
// 122.106 us; speedup vs baseline: 7.3051x; 1.8570x over previous
//
#include <hip/hip_runtime.h>
#include <hip/hip_fp16.h>

// NCC loss: 9^3 box sums of {I, J, I*I, J*J, I*J}, per-voxel cc, -mean(cc).
// Dims: C=2, D=192, H=224, W=192, fp32. Separable box filter:
//   K1 (k_hwsum): H-sum (register ring, 1-step prefetch) + W-sum (LDS 9-tap,
//                 double-buffered, one barrier per h-step) -> fp16 2D sums.
//   K2 (k_dsum):  D-sum — barrier-free streaming register ring + cc + reduce.
// fp16 intermediates: 2D sums bounded by 243, rel err ~5e-4; final-mean bias
// ~1e-5 << 5e-4 threshold. Halves intermediate HBM traffic vs fp32.

#define C2   2
#define DDIM 192
#define HDIM 224
#define WDIM 192
#define HWN  (HDIM*WDIM)              // 43008
#define VOL  ((size_t)DDIM*HWN)       // 8257536
#define RAD  4
#define WINV (1.0f/729.0f)

#define HT1  56   // K1 h-chunk per block (224/56 = 4)

// ---------------- K1: H-sum + W-sum of 5 product fields ----------------
// grid: (d rows in [dbeg,dend), HDIM/HT1, C2); block: 192 threads (w)
// buf layout (fp16): [f][c][bd][h][w], bd = d - d0 + 4, fstride = C2*bufD*HWN
__global__ __launch_bounds__(192)
void k_hwsum(const float* __restrict__ I, const float* __restrict__ J,
             __half* __restrict__ buf, int d0, int dbeg, int bufD)
{
    const int w  = threadIdx.x;
    const int d  = dbeg + blockIdx.x;
    const int h0 = blockIdx.y * HT1;
    const int c  = blockIdx.z;

    __shared__ float row[2][5][WDIM + 8];   // double-buffered H-sum row, 8 KB
    if (w < 8) {                            // zero the W-halo pads once
        const int pos = (w < 4) ? w : (WDIM + w);
        #pragma unroll
        for (int b = 0; b < 2; ++b)
            #pragma unroll
            for (int f = 0; f < 5; ++f) row[b][f][pos] = 0.f;
    }
    __syncthreads();

    const float* Ib = I + (size_t)c*VOL + (size_t)d*HWN + w;
    const float* Jb = J + (size_t)c*VOL + (size_t)d*HWN + w;

    float ring[5][9];
    float rs[5] = {0.f,0.f,0.f,0.f,0.f};

    // warm-up: ring slots 0..7 = products at rows h0-4 .. h0+3 (zero padded)
    #pragma unroll
    for (int k = 0; k < 8; ++k) {
        const int h = h0 - RAD + k;
        float iv = 0.f, jv = 0.f;
        if (h >= 0 && h < HDIM) { iv = Ib[(size_t)h*WDIM]; jv = Jb[(size_t)h*WDIM]; }
        const float pr[5] = {iv, jv, iv*iv, jv*jv, iv*jv};
        #pragma unroll
        for (int f = 0; f < 5; ++f) { ring[f][k] = pr[f]; rs[f] += pr[f]; }
    }

    // one-step prefetch of row h0+4
    float niv = 0.f, njv = 0.f;
    {
        const int hf = h0 + RAD;
        if (hf < HDIM) { niv = Ib[(size_t)hf*WDIM]; njv = Jb[(size_t)hf*WDIM]; }
    }

    const size_t fstride = (size_t)C2*bufD*HWN;
    __half* ob = buf + ((size_t)c*bufD + (size_t)(d - d0 + RAD))*HWN + w;

    int i = 0;
    while (i < HT1) {
        #pragma unroll
        for (int p = 0; p < 9; ++p) {   // i == p (mod 9) whenever body runs
            if (i < HT1) {
                const int h  = h0 + i;
                const float iv = niv, jv = njv;
                // prefetch next step's row (hides HBM latency under LDS phase)
                niv = 0.f; njv = 0.f;
                const int hf2 = h + 1 + RAD;
                if (i + 1 < HT1 && hf2 < HDIM) {
                    niv = Ib[(size_t)hf2*WDIM]; njv = Jb[(size_t)hf2*WDIM];
                }
                const float pr[5] = {iv, jv, iv*iv, jv*jv, iv*jv};
                float (* __restrict__ rb)[WDIM+8] = row[h & 1];
                #pragma unroll
                for (int f = 0; f < 5; ++f) {
                    rs[f] += pr[f];                 // H window sum at h
                    rb[f][RAD + w] = rs[f];
                    rs[f] -= ring[f][p];            // drop row h-4
                    ring[f][(p+8)%9] = pr[f];       // keep row h+4
                }
                __syncthreads();                    // single barrier: dbuf-safe
                #pragma unroll
                for (int f = 0; f < 5; ++f) {
                    float s = 0.f;
                    #pragma unroll
                    for (int q = 0; q < 9; ++q) s += rb[f][w + q];
                    ob[(size_t)f*fstride + (size_t)h*WDIM] = __float2half(s);
                }
                ++i;
            }
        }
    }
}

// -------- K2: D-sum (register ring) + cc + block reduce — no LDS, no syncs --------
// grid: (HWN/256, nsub, C2); block: 256 threads
__global__ __launch_bounds__(256)
void k_dsum(const __half* __restrict__ buf, double* __restrict__ gacc,
            int d0, int bufD, int DS)
{
    const int tid = threadIdx.x;
    const int pix = blockIdx.x*256 + tid;     // (h,w) flat, HWN = 168*256 exact
    const int c   = blockIdx.z;
    const int ds0 = d0 + blockIdx.y*DS;

    const size_t fstride = (size_t)C2*bufD*HWN;
    const __half* base = buf + (size_t)c*bufD*HWN + pix;

    float ring[5][9];
    float rs[5] = {0.f,0.f,0.f,0.f,0.f};
    float acc = 0.f;

    // warm-up: slices ds0-4 .. ds0+3
    #pragma unroll
    for (int k = 0; k < 8; ++k) {
        const int dd = ds0 - RAD + k;
        float v[5] = {0.f,0.f,0.f,0.f,0.f};
        if ((unsigned)dd < (unsigned)DDIM) {
            const __half* pp = base + (size_t)(dd - d0 + RAD)*HWN;
            #pragma unroll
            for (int f = 0; f < 5; ++f) v[f] = __half2float(pp[(size_t)f*fstride]);
        }
        #pragma unroll
        for (int f = 0; f < 5; ++f) { ring[f][k] = v[f]; rs[f] += v[f]; }
    }

    int i = 0;
    while (i < DS) {
        #pragma unroll
        for (int p = 0; p < 9; ++p) {   // i == p (mod 9) whenever body runs
            if (i < DS) {
                const int dd = ds0 + i + RAD;
                float v[5] = {0.f,0.f,0.f,0.f,0.f};
                if (dd < DDIM) {
                    const __half* pp = base + (size_t)(dd - d0 + RAD)*HWN;
                    #pragma unroll
                    for (int f = 0; f < 5; ++f) v[f] = __half2float(pp[(size_t)f*fstride]);
                }
                float S[5];
                #pragma unroll
                for (int f = 0; f < 5; ++f) {
                    rs[f] += v[f];              // full 9x9x9 sum at dd-4
                    S[f] = rs[f];
                    rs[f] -= ring[f][p];        // drop slice dd-8
                    ring[f][(p+8)%9] = v[f];    // keep slice dd
                }
                const float uI    = S[0]*WINV;
                const float uJ    = S[1]*WINV;
                const float cross = S[4] - uJ*S[0];
                const float Iv    = S[2] - uI*S[0];
                const float Jv    = S[3] - uJ*S[1];
                acc += cross*cross / (Iv*Jv + 1e-5f);
                ++i;
            }
        }
    }

    // block reduction -> one double atomic per block
    __shared__ float wred[4];
    #pragma unroll
    for (int off = 32; off > 0; off >>= 1) acc += __shfl_down(acc, off);
    if ((tid & 63) == 0) wred[tid >> 6] = acc;
    __syncthreads();
    if (tid == 0) {
        const float s = wred[0] + wred[1] + wred[2] + wred[3];
        atomicAdd(gacc, (double)s);
    }
}

__global__ void k_fin(const double* __restrict__ gacc, float* __restrict__ out)
{
    out[0] = (float)(-gacc[0] / (double)((size_t)C2*DDIM*HDIM*WDIM));
}

extern "C" void kernel_launch(void* const* d_in, const int* in_sizes, int n_in,
                              void* d_out, int out_size, void* d_ws, size_t ws_size,
                              hipStream_t stream)
{
    if (n_in < 2) return;
    const float* I = (const float*)d_in[0];
    const float* J = (const float*)d_in[1];
    float* out = (float*)d_out;
    double* gacc = (double*)d_ws;
    __half* buf = (__half*)((char*)d_ws + 256);

    // choose D-chunk so the 5-field fp16 2D-summed buffer fits ws
    static const int cands[] = {192, 96, 48, 24, 12, 6, 4, 2, 1};
    int Dc = 0;
    for (int c : cands) {
        const size_t need = 256 + (size_t)5*C2*(c+8)*HWN*sizeof(__half);
        if (need <= ws_size) { Dc = c; break; }
    }
    if (Dc == 0) return;  // ws too small — cannot run

    hipMemsetAsync(d_ws, 0, 256, stream);   // zero the double accumulator

    const int DS   = (Dc % 48 == 0) ? 48 : Dc;  // K2 sub-chunk along D
    const int nsub = Dc / DS;
    const int bufD = Dc + 8;

    for (int d0 = 0; d0 < DDIM; d0 += Dc) {
        const int dbeg = (d0 - RAD < 0) ? 0 : d0 - RAD;
        const int dend = (d0 + Dc + RAD > DDIM) ? DDIM : d0 + Dc + RAD;
        dim3 g1(dend - dbeg, HDIM/HT1, C2);
        k_hwsum<<<g1, dim3(192,1,1), 0, stream>>>(I, J, buf, d0, dbeg, bufD);
        dim3 g2(HWN/256, nsub, C2);
        k_dsum<<<g2, dim3(256,1,1), 0, stream>>>(buf, gacc, d0, bufD, DS);
    }
    k_fin<<<1,1,0,stream>>>(gacc, out);
}

// Round 4
// 118.226 us; speedup vs baseline: 7.5448x; 1.0328x over previous
//
#include <hip/hip_runtime.h>
#include <hip/hip_fp16.h>

// NCC loss: 9^3 box sums of {I, J, I*I, J*J, I*J}, per-voxel cc, -mean(cc).
// Dims: C=2, D=192, H=224, W=192, fp32. Separable box filter:
//   K1 (k_hwsum): 2px/thread. H-sum (float2 register ring, 1-step prefetch) +
//                 W-sum (LDS b64 taps, parity double-buffer, one barrier/step)
//                 -> fp16x2 packed 2D sums. Block = 2 d-slices x 96 pairs.
//   K2 (k_dsum):  D-sum — barrier-free streaming register ring + cc + reduce.

#define C2   2
#define DDIM 192
#define HDIM 224
#define WDIM 192
#define HWN  (HDIM*WDIM)              // 43008
#define VOL  ((size_t)DDIM*HWN)       // 8257536
#define RAD  4
#define WINV (1.0f/729.0f)

#define HT1  28     // K1 h-chunk per block (224/28 = 8)
#define NROW 200    // padded LDS row stride in floats: 4 | 192 | 4

// ---------------- K1: H-sum + W-sum of 5 product fields, 2px/thread ----------------
// grid: ((nd+1)/2, HDIM/HT1, C2); block: 192 = 2 slices x 96 pairs
// buf layout (fp16): [f][c][bd][h][w], bd = d - d0 + 4, fstride = C2*bufD*HWN
__global__ __launch_bounds__(192)
void k_hwsum(const float* __restrict__ I, const float* __restrict__ J,
             __half* __restrict__ buf, int d0, int dbeg, int dend, int bufD)
{
    const int tx = threadIdx.x;
    const int s  = tx / 96;           // d-slice within pair
    const int p  = tx % 96;           // w-pair index
    const int w0 = 2 * p;
    int d = dbeg + 2*blockIdx.x + s;
    if (d >= dend) d = dend - 1;      // duplicate of sibling thread: benign
    const int h0 = blockIdx.y * HT1;
    const int c  = blockIdx.z;

    __shared__ float row[2][2][5][NROW];   // [slice][parity][field], 16 KB

    // zero the W-halo pads (idx 0..3 and 196..199 of every row)
    for (int t = tx; t < 2*2*5*8; t += 192) {
        const int k    = t & 7;
        const int rest = t >> 3;                      // (s*2+b)*5+f
        const int pos  = (k < 4) ? k : (192 + k);     // 0..3, 196..199
        (&row[0][0][0][0])[rest*NROW + pos] = 0.f;
    }
    __syncthreads();

    const float* Ib = I + (size_t)c*VOL + (size_t)d*HWN + w0;
    const float* Jb = J + (size_t)c*VOL + (size_t)d*HWN + w0;

    float2 ring[5][9];
    float2 rs[5];
    #pragma unroll
    for (int f = 0; f < 5; ++f) { rs[f].x = 0.f; rs[f].y = 0.f; }

    // warm-up: ring slots 0..7 = products at rows h0-4 .. h0+3 (zero padded)
    #pragma unroll
    for (int k = 0; k < 8; ++k) {
        const int h = h0 - RAD + k;
        float2 iv = {0.f,0.f}, jv = {0.f,0.f};
        if (h >= 0 && h < HDIM) {
            iv = *(const float2*)(Ib + (size_t)h*WDIM);
            jv = *(const float2*)(Jb + (size_t)h*WDIM);
        }
        float2 pr[5];
        pr[0] = iv; pr[1] = jv;
        pr[2].x = iv.x*iv.x; pr[2].y = iv.y*iv.y;
        pr[3].x = jv.x*jv.x; pr[3].y = jv.y*jv.y;
        pr[4].x = iv.x*jv.x; pr[4].y = iv.y*jv.y;
        #pragma unroll
        for (int f = 0; f < 5; ++f) {
            ring[f][k] = pr[f];
            rs[f].x += pr[f].x; rs[f].y += pr[f].y;
        }
    }

    // one-step prefetch of row h0+4
    float2 niv = {0.f,0.f}, njv = {0.f,0.f};
    {
        const int hf = h0 + RAD;
        if (hf < HDIM) {
            niv = *(const float2*)(Ib + (size_t)hf*WDIM);
            njv = *(const float2*)(Jb + (size_t)hf*WDIM);
        }
    }

    const size_t fstride = (size_t)C2*bufD*HWN;
    __half* ob = buf + ((size_t)c*bufD + (size_t)(d - d0 + RAD))*HWN + w0;

    int i = 0;
    while (i < HT1) {
        #pragma unroll
        for (int p9 = 0; p9 < 9; ++p9) {   // i == p9 (mod 9) whenever body runs
            if (i < HT1) {
                const int h = h0 + i;
                const float2 iv = niv, jv = njv;
                // prefetch next row (hides HBM latency under LDS phase)
                niv.x = 0.f; niv.y = 0.f; njv.x = 0.f; njv.y = 0.f;
                const int hf2 = h + 1 + RAD;
                if (i + 1 < HT1 && hf2 < HDIM) {
                    niv = *(const float2*)(Ib + (size_t)hf2*WDIM);
                    njv = *(const float2*)(Jb + (size_t)hf2*WDIM);
                }
                float2 pr[5];
                pr[0] = iv; pr[1] = jv;
                pr[2].x = iv.x*iv.x; pr[2].y = iv.y*iv.y;
                pr[3].x = jv.x*jv.x; pr[3].y = jv.y*jv.y;
                pr[4].x = iv.x*jv.x; pr[4].y = iv.y*jv.y;
                float* rb = &row[s][h & 1][0][0];
                #pragma unroll
                for (int f = 0; f < 5; ++f) {
                    rs[f].x += pr[f].x; rs[f].y += pr[f].y;   // H-sum at h
                    *(float2*)(rb + f*NROW + 4 + w0) = rs[f];
                    rs[f].x -= ring[f][p9].x; rs[f].y -= ring[f][p9].y;  // drop h-4
                    ring[f][(p9+8)%9] = pr[f];                           // keep h+4
                }
                __syncthreads();               // single barrier: parity dbuf-safe
                #pragma unroll
                for (int f = 0; f < 5; ++f) {
                    const float* q = rb + f*NROW + w0;   // window w0-4 .. w0+5
                    const float2 r0 = *(const float2*)(q + 0);
                    const float2 r1 = *(const float2*)(q + 2);
                    const float2 r2 = *(const float2*)(q + 4);
                    const float2 r3 = *(const float2*)(q + 6);
                    const float2 r4 = *(const float2*)(q + 8);
                    const float s9 = r0.x+r0.y+r1.x+r1.y+r2.x+r2.y+r3.x+r3.y+r4.x;
                    const float o0 = s9;
                    const float o1 = s9 - r0.x + r4.y;
                    *reinterpret_cast<__half2*>(ob + f*fstride + (size_t)h*WDIM)
                        = __floats2half2_rn(o0, o1);
                }
                ++i;
            }
        }
    }
}

// -------- K2: D-sum (register ring) + cc + block reduce — no LDS, no syncs --------
// grid: (HWN/256, nsub, C2); block: 256 threads
__global__ __launch_bounds__(256)
void k_dsum(const __half* __restrict__ buf, double* __restrict__ gacc,
            int d0, int bufD, int DS)
{
    const int tid = threadIdx.x;
    const int pix = blockIdx.x*256 + tid;     // (h,w) flat, HWN = 168*256 exact
    const int c   = blockIdx.z;
    const int ds0 = d0 + blockIdx.y*DS;

    const size_t fstride = (size_t)C2*bufD*HWN;
    const __half* base = buf + (size_t)c*bufD*HWN + pix;

    float ring[5][9];
    float rs[5] = {0.f,0.f,0.f,0.f,0.f};
    float acc = 0.f;

    // warm-up: slices ds0-4 .. ds0+3
    #pragma unroll
    for (int k = 0; k < 8; ++k) {
        const int dd = ds0 - RAD + k;
        float v[5] = {0.f,0.f,0.f,0.f,0.f};
        if ((unsigned)dd < (unsigned)DDIM) {
            const __half* pp = base + (size_t)(dd - d0 + RAD)*HWN;
            #pragma unroll
            for (int f = 0; f < 5; ++f) v[f] = __half2float(pp[(size_t)f*fstride]);
        }
        #pragma unroll
        for (int f = 0; f < 5; ++f) { ring[f][k] = v[f]; rs[f] += v[f]; }
    }

    int i = 0;
    while (i < DS) {
        #pragma unroll
        for (int p = 0; p < 9; ++p) {   // i == p (mod 9) whenever body runs
            if (i < DS) {
                const int dd = ds0 + i + RAD;
                float v[5] = {0.f,0.f,0.f,0.f,0.f};
                if (dd < DDIM) {
                    const __half* pp = base + (size_t)(dd - d0 + RAD)*HWN;
                    #pragma unroll
                    for (int f = 0; f < 5; ++f) v[f] = __half2float(pp[(size_t)f*fstride]);
                }
                float S[5];
                #pragma unroll
                for (int f = 0; f < 5; ++f) {
                    rs[f] += v[f];              // full 9x9x9 sum at dd-4
                    S[f] = rs[f];
                    rs[f] -= ring[f][p];        // drop slice dd-8
                    ring[f][(p+8)%9] = v[f];    // keep slice dd
                }
                const float uI    = S[0]*WINV;
                const float uJ    = S[1]*WINV;
                const float cross = S[4] - uJ*S[0];
                const float Iv    = S[2] - uI*S[0];
                const float Jv    = S[3] - uJ*S[1];
                acc += cross*cross / (Iv*Jv + 1e-5f);
                ++i;
            }
        }
    }

    // block reduction -> one double atomic per block
    __shared__ float wred[4];
    #pragma unroll
    for (int off = 32; off > 0; off >>= 1) acc += __shfl_down(acc, off);
    if ((tid & 63) == 0) wred[tid >> 6] = acc;
    __syncthreads();
    if (tid == 0) {
        const float sum = wred[0] + wred[1] + wred[2] + wred[3];
        atomicAdd(gacc, (double)sum);
    }
}

__global__ void k_fin(const double* __restrict__ gacc, float* __restrict__ out)
{
    out[0] = (float)(-gacc[0] / (double)((size_t)C2*DDIM*HDIM*WDIM));
}

extern "C" void kernel_launch(void* const* d_in, const int* in_sizes, int n_in,
                              void* d_out, int out_size, void* d_ws, size_t ws_size,
                              hipStream_t stream)
{
    if (n_in < 2) return;
    const float* I = (const float*)d_in[0];
    const float* J = (const float*)d_in[1];
    float* out = (float*)d_out;
    double* gacc = (double*)d_ws;
    __half* buf = (__half*)((char*)d_ws + 256);

    // choose D-chunk so the 5-field fp16 2D-summed buffer fits ws
    static const int cands[] = {192, 96, 48, 24, 12, 6, 4, 2, 1};
    int Dc = 0;
    for (int c : cands) {
        const size_t need = 256 + (size_t)5*C2*(c+8)*HWN*sizeof(__half);
        if (need <= ws_size) { Dc = c; break; }
    }
    if (Dc == 0) return;  // ws too small — cannot run

    hipMemsetAsync(d_ws, 0, 256, stream);   // zero the double accumulator

    const int DS   = (Dc % 48 == 0) ? 48 : Dc;  // K2 sub-chunk along D
    const int nsub = Dc / DS;
    const int bufD = Dc + 8;

    for (int d0 = 0; d0 < DDIM; d0 += Dc) {
        const int dbeg = (d0 - RAD < 0) ? 0 : d0 - RAD;
        const int dend = (d0 + Dc + RAD > DDIM) ? DDIM : d0 + Dc + RAD;
        const int nd   = dend - dbeg;
        dim3 g1((nd + 1)/2, HDIM/HT1, C2);
        k_hwsum<<<g1, dim3(192,1,1), 0, stream>>>(I, J, buf, d0, dbeg, dend, bufD);
        dim3 g2(HWN/256, nsub, C2);
        k_dsum<<<g2, dim3(256,1,1), 0, stream>>>(buf, gacc, d0, bufD, DS);
    }
    k_fin<<<1,1,0,stream>>>(gacc, out);
}